// Round 1
// baseline (58.307 us; speedup 1.0000x reference)
//
#include <hip/hip_runtime.h>
#include <math.h>

#define FDIM 512
#define NL 1600
#define NR 64

// K1: fused first-layer GEMMs.
//  A-part (blocks bm 0..49):  A[l][n] = sum_f SL[idxL[l]][f] * W1[f][n]
//  B-part (blocks bm 50..51): B[r][n] = b1[n] + sum_f SR[idxR[r]][f] * W1[512+f][n]
__global__ __launch_bounds__(256) void k_lin1(
    const float* __restrict__ SL, const float* __restrict__ SR,
    const float* __restrict__ W1, const float* __restrict__ b1,
    const int* __restrict__ idxL, const int* __restrict__ idxR,
    float* __restrict__ Aout, float* __restrict__ Bout)
{
    __shared__ float As[32][34];   // [k][m], padded: 34*4B=136B row stride -> 8B aligned + conflict-free
    __shared__ float Bs[32][32];   // [k][n]
    const int t  = threadIdx.x;
    const int bn = blockIdx.y;              // 0..15
    const int bm = blockIdx.x;              // 0..51
    const bool isB = (bm >= 50);
    const float* src = isB ? SR : SL;
    const int*   idx = isB ? idxR : idxL;
    const float* wb  = isB ? (W1 + FDIM * FDIM) : W1;
    float*       out = isB ? Bout : Aout;
    const int m0 = (isB ? (bm - 50) : bm) * 32;
    const int n0 = bn * 32;

    const int mrow = t >> 3;          // 0..31  (staging row / W1 k-row)
    const int kq   = (t & 7) << 2;    // 0,4,...,28
    const long grow = idx[m0 + mrow]; // gathered source row (reused every k-step)

    const int tm = t >> 4;            // 0..15
    const int tn = t & 15;            // 0..15

    float acc00 = 0.f, acc01 = 0.f, acc10 = 0.f, acc11 = 0.f;

    for (int k0 = 0; k0 < FDIM; k0 += 32) {
        float4 va = *reinterpret_cast<const float4*>(&src[grow * FDIM + k0 + kq]);
        float4 vb = *reinterpret_cast<const float4*>(&wb[(long)(k0 + mrow) * FDIM + n0 + kq]);
        As[kq + 0][mrow] = va.x;
        As[kq + 1][mrow] = va.y;
        As[kq + 2][mrow] = va.z;
        As[kq + 3][mrow] = va.w;
        *reinterpret_cast<float4*>(&Bs[mrow][kq]) = vb;
        __syncthreads();
        #pragma unroll
        for (int kk = 0; kk < 32; ++kk) {
            float2 a = *reinterpret_cast<const float2*>(&As[kk][tm * 2]);
            float2 b = *reinterpret_cast<const float2*>(&Bs[kk][tn * 2]);
            acc00 = fmaf(a.x, b.x, acc00);
            acc01 = fmaf(a.x, b.y, acc01);
            acc10 = fmaf(a.y, b.x, acc10);
            acc11 = fmaf(a.y, b.y, acc11);
        }
        __syncthreads();
    }

    const int col = n0 + tn * 2;
    float bx = 0.f, by = 0.f;
    if (isB) { bx = b1[col]; by = b1[col + 1]; }
    float2 r0 = make_float2(acc00 + bx, acc01 + by);
    float2 r1 = make_float2(acc10 + bx, acc11 + by);
    *reinterpret_cast<float2*>(&out[(long)(m0 + tm * 2) * FDIM + col])     = r0;
    *reinterpret_cast<float2*>(&out[(long)(m0 + tm * 2 + 1) * FDIM + col]) = r1;
}

// K2: pairwise relu-dot + sigmoid.
// out[l][r] = sigmoid( sum_k relu(A[l,k]+B[r,k]) * wd[k] + b2d )
__global__ __launch_bounds__(256) void k_pair(
    const float* __restrict__ A, const float* __restrict__ Bm,
    const float* __restrict__ W2, const float* __restrict__ b2,
    float* __restrict__ out)
{
    __shared__ float Al[8][512];    // 16 KB, reads are wave-broadcast (same addr)
    __shared__ float Bs[64][128];   // 32 KB, per-float XOR swizzle -> conflict-free column reads
    __shared__ float wd[512];       // 2 KB
    const int t  = threadIdx.x;
    const int l0 = blockIdx.x * 8;

    #pragma unroll
    for (int i = 0; i < 4; ++i) {
        int lin4 = i * 256 + t;
        int l  = lin4 >> 7;
        int kf = (lin4 & 127) << 2;
        *reinterpret_cast<float4*>(&Al[l][kf]) =
            *reinterpret_cast<const float4*>(&A[(long)(l0 + l) * 512 + kf]);
    }
    wd[t]       = W2[2 * t + 1]         - W2[2 * t];
    wd[t + 256] = W2[2 * (t + 256) + 1] - W2[2 * (t + 256)];
    const float b2d = b2[1] - b2[0];

    const int r  = t & 63;
    const int lg = t >> 6;
    const int s  = r & 31;
    float acc0 = 0.f, acc1 = 0.f;

    for (int c = 0; c < 4; ++c) {
        __syncthreads();   // protect previous chunk (and, first time, nothing)
        #pragma unroll
        for (int i = 0; i < 8; ++i) {
            int lin4 = i * 256 + t;
            int rr = lin4 >> 5;
            int kf = (lin4 & 31) << 2;
            float4 v = *reinterpret_cast<const float4*>(&Bm[(long)rr * 512 + c * 128 + kf]);
            int ss = rr & 31;
            Bs[rr][(kf + 0) ^ ss] = v.x;
            Bs[rr][(kf + 1) ^ ss] = v.y;
            Bs[rr][(kf + 2) ^ ss] = v.z;
            Bs[rr][(kf + 3) ^ ss] = v.w;
        }
        __syncthreads();   // Bs (and on c==0, Al/wd) visible
        #pragma unroll 8
        for (int k = 0; k < 128; ++k) {
            float b  = Bs[r][k ^ s];
            float w  = wd[c * 128 + k];
            float a0 = Al[lg][c * 128 + k];
            float a1 = Al[lg + 4][c * 128 + k];
            acc0 = fmaf(fmaxf(a0 + b, 0.f), w, acc0);
            acc1 = fmaf(fmaxf(a1 + b, 0.f), w, acc1);
        }
    }
    float z0 = acc0 + b2d, z1 = acc1 + b2d;
    out[(long)(l0 + lg) * 64 + r]     = 1.f / (1.f + expf(-z0));
    out[(long)(l0 + lg + 4) * 64 + r] = 1.f / (1.f + expf(-z1));
}

extern "C" void kernel_launch(void* const* d_in, const int* in_sizes, int n_in,
                              void* d_out, int out_size, void* d_ws, size_t ws_size,
                              hipStream_t stream) {
    const float* SL  = (const float*)d_in[0];   // [200000,512]
    const float* SR  = (const float*)d_in[1];   // [100000,512]
    const float* W1  = (const float*)d_in[2];   // [1024,512]
    const float* b1  = (const float*)d_in[3];   // [512]
    const float* W2  = (const float*)d_in[4];   // [512,2]
    const float* b2  = (const float*)d_in[5];   // [2]
    const int*   idxL = (const int*)d_in[6];    // [1600]
    const int*   idxR = (const int*)d_in[7];    // [64]
    float* out = (float*)d_out;                 // [1600,64]

    float* A  = (float*)d_ws;                   // [1600,512] f32 = 3.28 MB
    float* Bm = A + (long)NL * FDIM;            // [64,512]  f32 = 128 KB

    k_lin1<<<dim3(52, 16), 256, 0, stream>>>(SL, SR, W1, b1, idxL, idxR, A, Bm);
    k_pair<<<NL / 8, 256, 0, stream>>>(A, Bm, W2, b2, out);
}

// Round 2
// 39.690 us; speedup vs baseline: 1.4691x; 1.4691x over previous
//
#include <hip/hip_runtime.h>
#include <math.h>

#define FDIM 512
#define NL 1600
#define NR 64
#define NM (NL + NR)   // 1664 gathered rows (first 1600 -> A via W1top, last 64 -> Bm via W1bot)

typedef __attribute__((ext_vector_type(8))) short short8;      // 8 bf16 bits = 4 VGPR (MFMA A/B frag)
typedef __attribute__((ext_vector_type(4))) float f32x4;       // MFMA C/D frag
typedef __attribute__((ext_vector_type(8))) unsigned short ushort8;
typedef __attribute__((ext_vector_type(4))) unsigned short ushort4v;

__device__ __forceinline__ unsigned short f2bf(float f) {
    unsigned u = __float_as_uint(f);
    u += 0x7fffu + ((u >> 16) & 1u);   // RNE
    return (unsigned short)(u >> 16);
}

// K0: prep. Blocks 0..415: gather+convert 4 rows each -> Abf[1664][512] bf16.
//     Blocks 416..927: transpose+convert W1 [1024][512] f32 -> WT[2][512][512] bf16, WT[h][n][k]=W1[h*512+k][n].
__global__ __launch_bounds__(256) void k_prep(
    const float* __restrict__ SL, const float* __restrict__ SR,
    const float* __restrict__ W1,
    const int* __restrict__ idxL, const int* __restrict__ idxR,
    unsigned short* __restrict__ Abf, unsigned short* __restrict__ WT)
{
    __shared__ float tile[32][33];
    const int t = threadIdx.x;
    if (blockIdx.x < 416) {
        const int rowi = blockIdx.x * 4 + (t >> 6);
        const int k0 = (t & 63) * 8;
        long srow; const float* sp;
        if (rowi < NL) { srow = idxL[rowi];      sp = SL; }
        else           { srow = idxR[rowi - NL]; sp = SR; }
        const float* p = sp + srow * FDIM + k0;
        float4 v0 = *(const float4*)(p);
        float4 v1 = *(const float4*)(p + 4);
        ushort8 o;
        o[0]=f2bf(v0.x); o[1]=f2bf(v0.y); o[2]=f2bf(v0.z); o[3]=f2bf(v0.w);
        o[4]=f2bf(v1.x); o[5]=f2bf(v1.y); o[6]=f2bf(v1.z); o[7]=f2bf(v1.w);
        *(ushort8*)(Abf + (long)rowi * FDIM + k0) = o;
    } else {
        const int bidx = blockIdx.x - 416;
        const int ktile = bidx >> 4;   // 0..31 over fk (1024/32)
        const int ntile = bidx & 15;   // 0..15 over n  (512/32)
        {
            const int r  = t >> 3;         // 0..31 (fk offset)
            const int c4 = (t & 7) * 4;    // 0..28 (n offset)
            float4 v = *(const float4*)(&W1[(long)(ktile*32 + r) * FDIM + ntile*32 + c4]);
            tile[r][c4+0]=v.x; tile[r][c4+1]=v.y; tile[r][c4+2]=v.z; tile[r][c4+3]=v.w;
        }
        __syncthreads();
        const int h  = ktile >> 4;               // which half of W1 (top/bot)
        const int kb = (ktile & 15) * 32;        // k base within half
        const int nl = t >> 3;                   // 0..31
        const int k4 = (t & 7) * 4;
        ushort4v o;
        o[0]=f2bf(tile[k4+0][nl]); o[1]=f2bf(tile[k4+1][nl]);
        o[2]=f2bf(tile[k4+2][nl]); o[3]=f2bf(tile[k4+3][nl]);
        *(ushort4v*)(WT + (long)h*FDIM*FDIM + (long)(ntile*32 + nl)*FDIM + kb + k4) = o;
    }
}

// K1: bf16 MFMA GEMM, no LDS. 1 wave/block, wave tile 32(M) x 64(N), K=512.
// bm 0..49 -> A rows, bm 50..51 -> Bm rows (+b1). Both fragments are 16B contiguous
// loads (Abf row-major in k; WT transposed so B-frag is also k-contiguous).
// A/B use the SAME slot->k mapping (row=lane&15, k=(lane>>4)*8+j) -> dot product
// correct for any consistent bijection; C/D layout per guide: col=lane&15, row=(lane>>4)*4+r.
__global__ __launch_bounds__(64) void k_mfma(
    const short* __restrict__ Abf, const short* __restrict__ WT,
    const float* __restrict__ b1, float* __restrict__ A, float* __restrict__ Bm)
{
    const int bm = blockIdx.x;     // 0..51
    const int bn = blockIdx.y;     // 0..7
    const bool isB = bm >= 50;
    const int m0 = bm * 32, n0 = bn * 64;
    const short* wt = WT + (isB ? (long)FDIM * FDIM : 0);
    const int lane = threadIdx.x;
    const int row = lane & 15, g = lane >> 4;

    f32x4 acc[2][4] = {};
    const short* aP = Abf + (long)(m0 + row) * FDIM + g * 8;
    const short* bP = wt  + (long)(n0 + row) * FDIM + g * 8;

    short8 a[2][2], b[2][4];
    #pragma unroll
    for (int i = 0; i < 2; i++) a[0][i] = *(const short8*)(aP + i * 16 * FDIM);
    #pragma unroll
    for (int j = 0; j < 4; j++) b[0][j] = *(const short8*)(bP + j * 16 * FDIM);

    #pragma unroll
    for (int kk = 0; kk < 16; ++kk) {
        const int cur = kk & 1, nxt = cur ^ 1;
        if (kk < 15) {
            const int ko = (kk + 1) * 32;
            #pragma unroll
            for (int i = 0; i < 2; i++) a[nxt][i] = *(const short8*)(aP + ko + i * 16 * FDIM);
            #pragma unroll
            for (int j = 0; j < 4; j++) b[nxt][j] = *(const short8*)(bP + ko + j * 16 * FDIM);
        }
        #pragma unroll
        for (int i = 0; i < 2; i++)
            #pragma unroll
            for (int j = 0; j < 4; j++)
                acc[i][j] = __builtin_amdgcn_mfma_f32_16x16x32_bf16(a[cur][i], b[cur][j], acc[i][j], 0, 0, 0);
    }

    #pragma unroll
    for (int i = 0; i < 2; i++) {
        #pragma unroll
        for (int j = 0; j < 4; j++) {
            #pragma unroll
            for (int r = 0; r < 4; r++) {
                const int m = m0 + i * 16 + g * 4 + r;
                const int n = n0 + j * 16 + row;
                const float v = acc[i][j][r];
                if (isB) Bm[(long)(m - NL) * FDIM + n] = v + b1[n];
                else     A [(long)m * FDIM + n] = v;
            }
        }
    }
}

// K2: pairwise relu-dot + sigmoid (unchanged from passing round).
// out[l][r] = sigmoid( sum_k relu(A[l,k]+B[r,k]) * wd[k] + b2d )
__global__ __launch_bounds__(256) void k_pair(
    const float* __restrict__ A, const float* __restrict__ Bm,
    const float* __restrict__ W2, const float* __restrict__ b2,
    float* __restrict__ out)
{
    __shared__ float Al[8][512];
    __shared__ float Bs[64][128];
    __shared__ float wd[512];
    const int t  = threadIdx.x;
    const int l0 = blockIdx.x * 8;

    #pragma unroll
    for (int i = 0; i < 4; ++i) {
        int lin4 = i * 256 + t;
        int l  = lin4 >> 7;
        int kf = (lin4 & 127) << 2;
        *reinterpret_cast<float4*>(&Al[l][kf]) =
            *reinterpret_cast<const float4*>(&A[(long)(l0 + l) * 512 + kf]);
    }
    wd[t]       = W2[2 * t + 1]         - W2[2 * t];
    wd[t + 256] = W2[2 * (t + 256) + 1] - W2[2 * (t + 256)];
    const float b2d = b2[1] - b2[0];

    const int r  = t & 63;
    const int lg = t >> 6;
    const int s  = r & 31;
    float acc0 = 0.f, acc1 = 0.f;

    for (int c = 0; c < 4; ++c) {
        __syncthreads();
        #pragma unroll
        for (int i = 0; i < 8; ++i) {
            int lin4 = i * 256 + t;
            int rr = lin4 >> 5;
            int kf = (lin4 & 31) << 2;
            float4 v = *reinterpret_cast<const float4*>(&Bm[(long)rr * 512 + c * 128 + kf]);
            int ss = rr & 31;
            Bs[rr][(kf + 0) ^ ss] = v.x;
            Bs[rr][(kf + 1) ^ ss] = v.y;
            Bs[rr][(kf + 2) ^ ss] = v.z;
            Bs[rr][(kf + 3) ^ ss] = v.w;
        }
        __syncthreads();
        #pragma unroll 8
        for (int k = 0; k < 128; ++k) {
            float b  = Bs[r][k ^ s];
            float w  = wd[c * 128 + k];
            float a0 = Al[lg][c * 128 + k];
            float a1 = Al[lg + 4][c * 128 + k];
            acc0 = fmaf(fmaxf(a0 + b, 0.f), w, acc0);
            acc1 = fmaf(fmaxf(a1 + b, 0.f), w, acc1);
        }
    }
    float z0 = acc0 + b2d, z1 = acc1 + b2d;
    out[(long)(l0 + lg) * 64 + r]     = 1.f / (1.f + expf(-z0));
    out[(long)(l0 + lg + 4) * 64 + r] = 1.f / (1.f + expf(-z1));
}

extern "C" void kernel_launch(void* const* d_in, const int* in_sizes, int n_in,
                              void* d_out, int out_size, void* d_ws, size_t ws_size,
                              hipStream_t stream) {
    const float* SL  = (const float*)d_in[0];   // [200000,512]
    const float* SR  = (const float*)d_in[1];   // [100000,512]
    const float* W1  = (const float*)d_in[2];   // [1024,512]
    const float* b1  = (const float*)d_in[3];   // [512]
    const float* W2  = (const float*)d_in[4];   // [512,2]
    const float* b2  = (const float*)d_in[5];   // [2]
    const int*   idxL = (const int*)d_in[6];    // [1600]
    const int*   idxR = (const int*)d_in[7];    // [64]
    float* out = (float*)d_out;                 // [1600,64]

    float* A  = (float*)d_ws;                         // [1600,512] f32
    float* Bm = A + (long)NL * FDIM;                  // [64,512]   f32
    unsigned short* Abf = (unsigned short*)(Bm + (long)NR * FDIM);  // [1664,512] bf16
    unsigned short* WT  = Abf + (long)NM * FDIM;                    // [2,512,512] bf16

    k_prep<<<928, 256, 0, stream>>>(SL, SR, W1, idxL, idxR, Abf, WT);
    k_mfma<<<dim3(52, 8), 64, 0, stream>>>((const short*)Abf, (const short*)WT, b1, A, Bm);
    k_pair<<<NL / 8, 256, 0, stream>>>(A, Bm, W2, b2, out);
}